// Round 3
// baseline (93.205 us; speedup 1.0000x reference)
//
#include <hip/hip_runtime.h>
#include <hip/hip_bf16.h>

// Problem constants (T=512, B=32, D=128, 9 table rows after clipping).
// positions uniform 0..15 -> ~50% of pairs clip to bucket 8.
#define TBPAIRS 16384
#define DEMB    128
#define NR      9
#define NBLK    64                  // bucketize blocks (256 pairs each)
#define CHUNK   128                 // pairs per virtual work item in kernel 2
#define NCHUNK  (TBPAIRS / CHUNK)   // 128 chunks per bucket
#define NVIRT   (NR * NCHUNK)       // 1152 virtual work items
#define GRID2   512                 // 2 blocks/CU

#define BPACK_U4    (NR * 2048)           // 18432 uint4 = 288 KB
#define BPACK_BYTES (BPACK_U4 * 16)       // 294912
#define HIST_OFF    BPACK_BYTES           // 64*9 ints = 2304 B
#define LPERM_OFF   (HIST_OFF + 4096)     // 9*64*256 ints = 576 KB

using short8 = __attribute__((ext_vector_type(8))) short;
using f32x4  = __attribute__((ext_vector_type(4))) float;

// fp32 -> bf16 round-to-nearest-even
__device__ __forceinline__ unsigned short f2bf(float f) {
    unsigned u = __float_as_uint(f);
    u = u + 0x7FFFu + ((u >> 16) & 1u);
    return (unsigned short)(u >> 16);
}

// ---------------------------------------------------------------------------
// Kernel 1 (no global atomics, no pre-zeroed state):
//   blocks 0..63  -> bucketize: lperm[(r*64+bid)*256 + rank] = pair,
//                    hist[bid*9+r] = count
//   blocks 64..99 -> pack table row r=(bid-64)>>2, segment (bid-64)&3 into
//                    bf16 B-fragment order for mfma_f32_16x16x32_bf16:
//   uint4 index r*2048 + nt*256 + ks*64 + lane holds
//   M[r][d = ks*32 + (lane>>4)*8 + j][e = nt*16 + (lane&15)], j=0..7
// ---------------------------------------------------------------------------
__global__ __launch_bounds__(256) void prep_kernel(
    const int*   __restrict__ positions,
    const float* __restrict__ table,
    uint4* __restrict__ bpack,
    int*   __restrict__ hist,
    int*   __restrict__ lperm) {

    const int bid = blockIdx.x;
    const int tid = threadIdx.x;

    if (bid < NBLK) {
        __shared__ int cnt[NR];
        if (tid < NR) cnt[tid] = 0;
        __syncthreads();
        const int pair = bid * 256 + tid;
        const int p = positions[pair];
        const int r = (p < 8) ? p : 8;
        const int rank = atomicAdd(&cnt[r], 1);   // LDS atomic only
        lperm[(r * NBLK + bid) * 256 + rank] = pair;
        __syncthreads();
        if (tid < NR) hist[bid * NR + tid] = cnt[tid];
    } else {
        const int pid = bid - NBLK;
        const int r   = pid >> 2;
        const int seg = pid & 3;
        const float* M = table + r * DEMB * DEMB;
#pragma unroll
        for (int k = 0; k < 2; ++k) {
            const int idx  = seg * 512 + k * 256 + tid;  // 0..2047 within row
            const int lane = idx & 63;
            const int ks   = (idx >> 6) & 3;
            const int nt   = idx >> 8;
            const int e    = nt * 16 + (lane & 15);
            const int d0   = ks * 32 + (lane >> 4) * 8;
            union { unsigned short us[8]; uint4 v; } u;
#pragma unroll
            for (int j = 0; j < 8; ++j)
                u.us[j] = f2bf(M[(d0 + j) * DEMB + e]);
            bpack[r * 2048 + idx] = u.v;
        }
    }
}

// ---------------------------------------------------------------------------
// Kernel 2: virtual items v = (r = v%9, chunk = v/9), chunk = 128 pairs.
// Each wave computes TWO 16-pair m-tiles against one shared B-fragment load.
// Rank->pair mapping via LDS prefix-sum over the 64x9 histogram + 6-step
// binary search (no global counter reads).
// ---------------------------------------------------------------------------
__global__ __launch_bounds__(256) void transfer_kernel(
    const float* __restrict__ x,
    const uint4* __restrict__ bpack,
    const int*   __restrict__ hist,
    const int*   __restrict__ lperm,
    float*       __restrict__ out) {

    __shared__ int lhist[NBLK * NR];   // [bid][r]
    __shared__ int ps[NR * 65];        // exclusive prefix per r over bid; [r*65+64]=total

    const int tid = threadIdx.x;

    for (int i = tid; i < NBLK * NR; i += 256) lhist[i] = hist[i];
    __syncthreads();
    if (tid < NR) {
        int acc = 0;
        for (int b = 0; b < NBLK; ++b) {
            ps[tid * 65 + b] = acc;
            acc += lhist[b * NR + tid];
        }
        ps[tid * 65 + 64] = acc;
    }
    __syncthreads();

    const int wave = tid >> 6;
    const int lane = tid & 63;
    const int m16  = lane & 15;   // m (pair-in-tile) for A; n (col) for C/D
    const int quad = lane >> 4;

    for (int v = blockIdx.x; v < NVIRT; v += GRID2) {
        const int r     = v % NR;
        const int chunk = v / NR;
        const int c     = ps[r * 65 + 64];
        const int base  = chunk * CHUNK;
        if (base >= c) continue;            // dead item: LDS-only cost
        const int tb0 = base + wave * 32;   // this wave's first tile
        if (tb0 >= c) continue;

        // map concat-order rank g (0 <= g < c) -> pair index
        auto mapg = [&](int g) -> int {
            int lo = 0, hi = 64;
#pragma unroll
            for (int s = 0; s < 6; ++s) {
                const int mid = (lo + hi) >> 1;
                if (ps[r * 65 + mid] <= g) lo = mid; else hi = mid;
            }
            return lperm[(r * NBLK + lo) * 256 + (g - ps[r * 65 + lo])];
        };

        short8 a[2][4];
        int    prow[2][4];
        bool   pval[2][4];
        int    nmv[2];
#pragma unroll
        for (int s2 = 0; s2 < 2; ++s2) {
            const int tb = tb0 + 16 * s2;
            const int nm = c - tb;          // valid pairs in this tile
            nmv[s2] = nm;
            if (nm > 0) {
                // A frags: A[m = lane&15][k = ks*32 + quad*8 + j]
                const int slotA = mapg(tb + ((m16 < nm) ? m16 : 0));
                const float* xrow = x + (size_t)slotA * DEMB;
#pragma unroll
                for (int ks = 0; ks < 4; ++ks) {
                    const float4* s4 = (const float4*)(xrow + ks * 32 + quad * 8);
                    const float4 f0 = s4[0];
                    const float4 f1 = s4[1];
                    union { unsigned short us[8]; short8 s8; } ua;
                    ua.us[0] = f2bf(f0.x); ua.us[1] = f2bf(f0.y);
                    ua.us[2] = f2bf(f0.z); ua.us[3] = f2bf(f0.w);
                    ua.us[4] = f2bf(f1.x); ua.us[5] = f2bf(f1.y);
                    ua.us[6] = f2bf(f1.z); ua.us[7] = f2bf(f1.w);
                    a[s2][ks] = ua.s8;
                }
            }
            // C/D rows: col = lane&15, row m = quad*4 + i
#pragma unroll
            for (int i = 0; i < 4; ++i) {
                const int m = quad * 4 + i;
                pval[s2][i] = (nm > 0) && (m < nm);
                prow[s2][i] = pval[s2][i] ? mapg(tb + m) : 0;
            }
        }

        const uint4* bp  = bpack + r * 2048 + lane;
        const bool   two = nmv[1] > 0;      // wave-uniform
#pragma unroll 2
        for (int nt = 0; nt < 8; ++nt) {
            f32x4 acc0 = {0.f, 0.f, 0.f, 0.f};
            f32x4 acc1 = {0.f, 0.f, 0.f, 0.f};
#pragma unroll
            for (int ks = 0; ks < 4; ++ks) {
                union { uint4 v4; short8 s8; } ub;
                ub.v4 = bp[(nt * 4 + ks) * 64];
                acc0 = __builtin_amdgcn_mfma_f32_16x16x32_bf16(a[0][ks], ub.s8, acc0, 0, 0, 0);
                if (two)
                    acc1 = __builtin_amdgcn_mfma_f32_16x16x32_bf16(a[1][ks], ub.s8, acc1, 0, 0, 0);
            }
            const int col = nt * 16 + m16;
#pragma unroll
            for (int i = 0; i < 4; ++i)
                if (pval[0][i]) out[(size_t)prow[0][i] * DEMB + col] = acc0[i];
            if (two) {
#pragma unroll
                for (int i = 0; i < 4; ++i)
                    if (pval[1][i]) out[(size_t)prow[1][i] * DEMB + col] = acc1[i];
            }
        }
    }
}

extern "C" void kernel_launch(void* const* d_in, const int* in_sizes, int n_in,
                              void* d_out, int out_size, void* d_ws, size_t ws_size,
                              hipStream_t stream) {
    const int*   positions = (const int*)d_in[0];   // (16384,) int32
    const float* outputs   = (const float*)d_in[1]; // (16384, 128) fp32
    const float* table     = (const float*)d_in[2]; // (9, 128, 128) fp32
    float* out = (float*)d_out;                     // (16384, 128) fp32

    uint4* bpack = (uint4*)d_ws;
    int*   hist  = (int*)((char*)d_ws + HIST_OFF);
    int*   lperm = (int*)((char*)d_ws + LPERM_OFF);

    hipLaunchKernelGGL(prep_kernel, dim3(100), dim3(256), 0, stream,
                       positions, table, bpack, hist, lperm);
    hipLaunchKernelGGL(transfer_kernel, dim3(GRID2), dim3(256), 0, stream,
                       outputs, bpack, hist, lperm, out);
}

// Round 4
// 75.530 us; speedup vs baseline: 1.2340x; 1.2340x over previous
//
#include <hip/hip_runtime.h>
#include <hip/hip_bf16.h>

// Problem constants (T=512, B=32, D=128, 9 table rows after clipping).
// positions uniform 0..15 -> ~50% of pairs clip to bucket 8.
#define TBPAIRS 16384
#define DEMB    128
#define NR      9
#define CAP     16384              // per-bucket perm capacity (worst case)
#define GRID2   512                // 2 blocks/CU

#define BPACK_U4    (NR * 2048)          // 18432 uint4 = 288 KB
#define BPACK_BYTES (BPACK_U4 * 16)      // 294912

using short8 = __attribute__((ext_vector_type(8))) short;
using f32x4  = __attribute__((ext_vector_type(4))) float;

// fp32 -> bf16 round-to-nearest-even
__device__ __forceinline__ unsigned short f2bf(float f) {
    unsigned u = __float_as_uint(f);
    u = u + 0x7FFFu + ((u >> 16) & 1u);
    return (unsigned short)(u >> 16);
}

// ---------------------------------------------------------------------------
// Kernel 1 (R2-proven): blocks 0..63 -> global bucketize (perm + gcnt)
//                       blocks 64..99 -> pack table row (bid-64)>>2, seg &3
// B-fragment order for mfma_f32_16x16x32_bf16 (verified):
//   uint4 index r*2048 + nt*256 + ks*64 + lane holds
//   M[r][d = ks*32 + (lane>>4)*8 + j][e = nt*16 + (lane&15)], j=0..7
// ---------------------------------------------------------------------------
__global__ __launch_bounds__(256) void prep_kernel(
    const int*   __restrict__ positions,
    const float* __restrict__ table,
    uint4* __restrict__ bpack,
    int*   __restrict__ gcnt,   // 9 counters, pre-zeroed by memset node
    int*   __restrict__ perm) {

    const int bid = blockIdx.x;
    const int tid = threadIdx.x;

    if (bid < 64) {
        __shared__ int lcnt[NR];
        __shared__ int lbase[NR];
        if (tid < NR) lcnt[tid] = 0;
        __syncthreads();
        const int pair = bid * 256 + tid;
        const int p = positions[pair];
        const int r = (p < 8) ? p : 8;
        const int rank = atomicAdd(&lcnt[r], 1);
        __syncthreads();
        if (tid < NR) lbase[tid] = atomicAdd(&gcnt[tid], lcnt[tid]);
        __syncthreads();
        perm[r * CAP + lbase[r] + rank] = pair;
    } else {
        const int pid = bid - 64;
        const int r   = pid >> 2;
        const int seg = pid & 3;
        const float* M = table + r * DEMB * DEMB;
#pragma unroll
        for (int k = 0; k < 2; ++k) {
            const int idx  = seg * 512 + k * 256 + tid;  // 0..2047 within row
            const int lane = idx & 63;
            const int ks   = (idx >> 6) & 3;
            const int nt   = idx >> 8;
            const int e    = nt * 16 + (lane & 15);
            const int d0   = ks * 32 + (lane >> 4) * 8;
            union { unsigned short us[8]; uint4 v; } u;
#pragma unroll
            for (int j = 0; j < 8; ++j)
                u.us[j] = f2bf(M[(d0 + j) * DEMB + e]);
            bpack[r * 2048 + idx] = u.v;
        }
    }
}

// ---------------------------------------------------------------------------
// Kernel 2: direct tile-index dispatch. Per block: load 9 bucket counts,
// build 10-entry tile prefix (tp[r] = sum of ceil(c/16)); wave-slot
// T = bid*4+wave maps to (r, tile) -- every iteration is a live full tile,
// <=1 tile per wave (total ~1029 tiles < 2048 wave slots).
// ---------------------------------------------------------------------------
__global__ __launch_bounds__(256) void transfer_kernel(
    const float* __restrict__ x,
    const uint4* __restrict__ bpack,
    const int*   __restrict__ gcnt,
    const int*   __restrict__ perm,
    float*       __restrict__ out) {

    __shared__ int cs[NR];
    __shared__ int tp[NR + 1];

    const int tid = threadIdx.x;
    if (tid < NR) cs[tid] = gcnt[tid];
    __syncthreads();
    if (tid == 0) {
        int acc = 0;
#pragma unroll
        for (int r = 0; r < NR; ++r) { tp[r] = acc; acc += (cs[r] + 15) >> 4; }
        tp[NR] = acc;
    }
    __syncthreads();

    const int wave  = tid >> 6;
    const int lane  = tid & 63;
    const int m16   = lane & 15;   // m (pair-in-tile) for A; n (col) for C/D
    const int quad  = lane >> 4;
    const int total = tp[NR];

    for (int T = blockIdx.x * 4 + wave; T < total; T += GRID2 * 4) {
        // bucket lookup: 8 broadcast LDS reads + cndmask (no divergence)
        int r = 0;
#pragma unroll
        for (int rr = 1; rr < NR; ++rr) r = (T >= tp[rr]) ? rr : r;
        const int tb = (T - tp[r]) * 16;
        const int c  = cs[r];
        const int nm = c - tb;            // valid pairs in tile (1..16)
        const int* pr = perm + r * CAP + tb;

        // ---- A fragments: A[m = lane&15][k = ks*32 + quad*8 + j]
        const int slotA = pr[(m16 < nm) ? m16 : 0];
        const float* xrow = x + (size_t)slotA * DEMB;
        short8 a[4];
#pragma unroll
        for (int ks = 0; ks < 4; ++ks) {
            const float4* s4 = (const float4*)(xrow + ks * 32 + quad * 8);
            const float4 f0 = s4[0];
            const float4 f1 = s4[1];
            union { unsigned short us[8]; short8 s8; } ua;
            ua.us[0] = f2bf(f0.x); ua.us[1] = f2bf(f0.y);
            ua.us[2] = f2bf(f0.z); ua.us[3] = f2bf(f0.w);
            ua.us[4] = f2bf(f1.x); ua.us[5] = f2bf(f1.y);
            ua.us[6] = f2bf(f1.z); ua.us[7] = f2bf(f1.w);
            a[ks] = ua.s8;
        }

        // ---- C/D rows: col = lane&15, row m = quad*4 + i
        int  prow[4];
        bool pval[4];
#pragma unroll
        for (int i = 0; i < 4; ++i) {
            const int m = quad * 4 + i;
            pval[i] = m < nm;
            prow[i] = pval[i] ? pr[m] : 0;
        }

        const uint4* bp = bpack + r * 2048 + lane;
#pragma unroll 2
        for (int nt = 0; nt < 8; ++nt) {
            f32x4 acc = {0.f, 0.f, 0.f, 0.f};
#pragma unroll
            for (int ks = 0; ks < 4; ++ks) {
                union { uint4 v4; short8 s8; } ub;
                ub.v4 = bp[(nt * 4 + ks) * 64];
                acc = __builtin_amdgcn_mfma_f32_16x16x32_bf16(a[ks], ub.s8, acc, 0, 0, 0);
            }
            const int col = nt * 16 + m16;
#pragma unroll
            for (int i = 0; i < 4; ++i)
                if (pval[i])
                    __builtin_nontemporal_store(acc[i], &out[(size_t)prow[i] * DEMB + col]);
        }
    }
}

extern "C" void kernel_launch(void* const* d_in, const int* in_sizes, int n_in,
                              void* d_out, int out_size, void* d_ws, size_t ws_size,
                              hipStream_t stream) {
    const int*   positions = (const int*)d_in[0];   // (16384,) int32
    const float* outputs   = (const float*)d_in[1]; // (16384, 128) fp32
    const float* table     = (const float*)d_in[2]; // (9, 128, 128) fp32
    float* out = (float*)d_out;                     // (16384, 128) fp32

    uint4* bpack = (uint4*)d_ws;                            // 288 KB
    int*   gcnt  = (int*)((char*)d_ws + BPACK_BYTES);       // 9 ints (pad 64 B)
    int*   perm  = (int*)((char*)d_ws + BPACK_BYTES + 64);  // 9*16384 ints

    hipMemsetAsync((void*)gcnt, 0, 64, stream);
    hipLaunchKernelGGL(prep_kernel, dim3(100), dim3(256), 0, stream,
                       positions, table, bpack, gcnt, perm);
    hipLaunchKernelGGL(transfer_kernel, dim3(GRID2), dim3(256), 0, stream,
                       outputs, bpack, gcnt, perm, out);
}

// Round 5
// 75.498 us; speedup vs baseline: 1.2345x; 1.0004x over previous
//
#include <hip/hip_runtime.h>
#include <hip/hip_bf16.h>

// Problem constants (T=512, B=32, D=128, 9 table rows after clipping).
// positions uniform 0..15 -> ~50% of pairs clip to bucket 8.
#define TBPAIRS 16384
#define DEMB    128
#define NR      9
#define CAP     16384              // per-bucket perm capacity (worst case)
#define GRID2   512                // 2 blocks/CU

#define BPACK_U4    (NR * 2048)          // 18432 uint4 = 288 KB
#define BPACK_BYTES (BPACK_U4 * 16)      // 294912

#define LSTRIDE 130                // LDS row stride in bf16 elems (pad: quads hit disjoint bank octets)

using short8 = __attribute__((ext_vector_type(8))) short;
using f32x4  = __attribute__((ext_vector_type(4))) float;

// fp32 -> bf16 round-to-nearest-even
__device__ __forceinline__ unsigned short f2bf(float f) {
    unsigned u = __float_as_uint(f);
    u = u + 0x7FFFu + ((u >> 16) & 1u);
    return (unsigned short)(u >> 16);
}

// ---------------------------------------------------------------------------
// Kernel 1: blocks 0..63  -> global bucketize (perm + gcnt)  [R2/R4-proven]
//           blocks 64..99 -> pack table, one (r, ks) pair per block, via LDS:
//   stage 32 d-rows (d = ks*32 .. ks*32+31) coalesced float4 -> bf16 in LDS,
//   then assemble B-fragments with conflict-free u16 gathers.
// B-fragment order for mfma_f32_16x16x32_bf16 (verified R1-R4):
//   uint4 index r*2048 + nt*256 + ks*64 + lane holds
//   M[r][d = ks*32 + (lane>>4)*8 + j][e = nt*16 + (lane&15)], j=0..7
// ---------------------------------------------------------------------------
__global__ __launch_bounds__(256) void prep_kernel(
    const int*   __restrict__ positions,
    const float* __restrict__ table,
    uint4* __restrict__ bpack,
    int*   __restrict__ gcnt,   // 9 counters, pre-zeroed by memset node
    int*   __restrict__ perm) {

    const int bid = blockIdx.x;
    const int tid = threadIdx.x;

    if (bid < 64) {
        __shared__ int lcnt[NR];
        __shared__ int lbase[NR];
        if (tid < NR) lcnt[tid] = 0;
        __syncthreads();
        const int pair = bid * 256 + tid;
        const int p = positions[pair];
        const int r = (p < 8) ? p : 8;
        const int rank = atomicAdd(&lcnt[r], 1);
        __syncthreads();
        if (tid < NR) lbase[tid] = atomicAdd(&gcnt[tid], lcnt[tid]);
        __syncthreads();
        perm[r * CAP + lbase[r] + rank] = pair;
    } else {
        // ---- pack: block = (r, ks); stage rows d = ks*32 + [0,32) in LDS
        __shared__ unsigned short sm[32 * LSTRIDE];
        const int pid = bid - 64;      // 0..35
        const int r   = pid >> 2;
        const int ks  = pid & 3;
        const float* M = table + (r * DEMB + ks * 32) * DEMB;  // rows ld=0..31

        // coalesced load: 32 rows x 128 floats = 1024 float4, 4 per thread
#pragma unroll
        for (int f4 = 0; f4 < 4; ++f4) {
            const int id   = f4 * 256 + tid;   // 0..1023
            const int row  = id >> 5;          // 0..31
            const int col4 = id & 31;          // float4 within row
            const float4 v = ((const float4*)(M + row * DEMB))[col4];
            unsigned short* dst = &sm[row * LSTRIDE + col4 * 4];
            dst[0] = f2bf(v.x); dst[1] = f2bf(v.y);
            dst[2] = f2bf(v.z); dst[3] = f2bf(v.w);
        }
        __syncthreads();

        // fragment assembly: 512 uint4 per block, 2 per thread
#pragma unroll
        for (int f = 0; f < 2; ++f) {
            const int fid  = f * 256 + tid;    // 0..511
            const int nt   = fid >> 6;         // 0..7
            const int lane = fid & 63;
            const int e    = nt * 16 + (lane & 15);
            const int ld0  = (lane >> 4) * 8;  // local d base
            union { unsigned short us[8]; uint4 v; } u;
#pragma unroll
            for (int j = 0; j < 8; ++j)
                u.us[j] = sm[(ld0 + j) * LSTRIDE + e];
            bpack[r * 2048 + nt * 256 + ks * 64 + lane] = u.v;
        }
    }
}

// ---------------------------------------------------------------------------
// Kernel 2 (R4-proven, unchanged): direct tile-index dispatch.
// ---------------------------------------------------------------------------
__global__ __launch_bounds__(256) void transfer_kernel(
    const float* __restrict__ x,
    const uint4* __restrict__ bpack,
    const int*   __restrict__ gcnt,
    const int*   __restrict__ perm,
    float*       __restrict__ out) {

    __shared__ int cs[NR];
    __shared__ int tp[NR + 1];

    const int tid = threadIdx.x;
    if (tid < NR) cs[tid] = gcnt[tid];
    __syncthreads();
    if (tid == 0) {
        int acc = 0;
#pragma unroll
        for (int r = 0; r < NR; ++r) { tp[r] = acc; acc += (cs[r] + 15) >> 4; }
        tp[NR] = acc;
    }
    __syncthreads();

    const int wave  = tid >> 6;
    const int lane  = tid & 63;
    const int m16   = lane & 15;   // m (pair-in-tile) for A; n (col) for C/D
    const int quad  = lane >> 4;
    const int total = tp[NR];

    for (int T = blockIdx.x * 4 + wave; T < total; T += GRID2 * 4) {
        int r = 0;
#pragma unroll
        for (int rr = 1; rr < NR; ++rr) r = (T >= tp[rr]) ? rr : r;
        const int tb = (T - tp[r]) * 16;
        const int c  = cs[r];
        const int nm = c - tb;            // valid pairs in tile (1..16)
        const int* pr = perm + r * CAP + tb;

        // ---- A fragments: A[m = lane&15][k = ks*32 + quad*8 + j]
        const int slotA = pr[(m16 < nm) ? m16 : 0];
        const float* xrow = x + (size_t)slotA * DEMB;
        short8 a[4];
#pragma unroll
        for (int ks = 0; ks < 4; ++ks) {
            const float4* s4 = (const float4*)(xrow + ks * 32 + quad * 8);
            const float4 f0 = s4[0];
            const float4 f1 = s4[1];
            union { unsigned short us[8]; short8 s8; } ua;
            ua.us[0] = f2bf(f0.x); ua.us[1] = f2bf(f0.y);
            ua.us[2] = f2bf(f0.z); ua.us[3] = f2bf(f0.w);
            ua.us[4] = f2bf(f1.x); ua.us[5] = f2bf(f1.y);
            ua.us[6] = f2bf(f1.z); ua.us[7] = f2bf(f1.w);
            a[ks] = ua.s8;
        }

        // ---- C/D rows: col = lane&15, row m = quad*4 + i
        int  prow[4];
        bool pval[4];
#pragma unroll
        for (int i = 0; i < 4; ++i) {
            const int m = quad * 4 + i;
            pval[i] = m < nm;
            prow[i] = pval[i] ? pr[m] : 0;
        }

        const uint4* bp = bpack + r * 2048 + lane;
#pragma unroll 2
        for (int nt = 0; nt < 8; ++nt) {
            f32x4 acc = {0.f, 0.f, 0.f, 0.f};
#pragma unroll
            for (int ks = 0; ks < 4; ++ks) {
                union { uint4 v4; short8 s8; } ub;
                ub.v4 = bp[(nt * 4 + ks) * 64];
                acc = __builtin_amdgcn_mfma_f32_16x16x32_bf16(a[ks], ub.s8, acc, 0, 0, 0);
            }
            const int col = nt * 16 + m16;
#pragma unroll
            for (int i = 0; i < 4; ++i)
                if (pval[i])
                    __builtin_nontemporal_store(acc[i], &out[(size_t)prow[i] * DEMB + col]);
        }
    }
}

extern "C" void kernel_launch(void* const* d_in, const int* in_sizes, int n_in,
                              void* d_out, int out_size, void* d_ws, size_t ws_size,
                              hipStream_t stream) {
    const int*   positions = (const int*)d_in[0];   // (16384,) int32
    const float* outputs   = (const float*)d_in[1]; // (16384, 128) fp32
    const float* table     = (const float*)d_in[2]; // (9, 128, 128) fp32
    float* out = (float*)d_out;                     // (16384, 128) fp32

    uint4* bpack = (uint4*)d_ws;                            // 288 KB
    int*   gcnt  = (int*)((char*)d_ws + BPACK_BYTES);       // 9 ints (pad 64 B)
    int*   perm  = (int*)((char*)d_ws + BPACK_BYTES + 64);  // 9*16384 ints

    hipMemsetAsync((void*)gcnt, 0, 64, stream);
    hipLaunchKernelGGL(prep_kernel, dim3(100), dim3(256), 0, stream,
                       positions, table, bpack, gcnt, perm);
    hipLaunchKernelGGL(transfer_kernel, dim3(GRID2), dim3(256), 0, stream,
                       outputs, bpack, gcnt, perm, out);
}